// Round 1
// baseline (426.346 us; speedup 1.0000x reference)
//
#include <hip/hip_runtime.h>

// -------------------------------------------------------------------------
// Kernel 1: top-k channel mask from importance.
// jax.lax.top_k keeps the `keep` largest, ties broken toward lower index.
// Element i kept iff rank(i) < keep, where
//   rank(i) = #{j : imp[j] > imp[i]} + #{j < i : imp[j] == imp[i]}
// One block (1 wave, 64 lanes) per channel; importance (16 KB) is L2-hot.
// -------------------------------------------------------------------------
__global__ __launch_bounds__(64) void topk_mask_kernel(
    const float* __restrict__ imp, float* __restrict__ maskf,
    int D, int keep)
{
    const int i = blockIdx.x;
    const float vi = imp[i];
    int cnt = 0;
    for (int j = (int)threadIdx.x; j < D; j += 64) {
        const float vj = imp[j];
        cnt += (vj > vi) || (vj == vi && j < i);
    }
    // wave-64 butterfly reduce
    #pragma unroll
    for (int off = 32; off > 0; off >>= 1)
        cnt += __shfl_down(cnt, off, 64);
    if (threadIdx.x == 0)
        maskf[i] = (cnt < keep) ? 1.0f : 0.0f;
}

// -------------------------------------------------------------------------
// Kernel 2: elementwise sparse polynomial.
// y[d in mask]  = c0*x + c1*x^2 + c2*x^3   (Horner)
// y[d !in mask] = x
// One float4 per thread; mask float4 vector (4 KB) stays in L1/L2.
// -------------------------------------------------------------------------
__global__ __launch_bounds__(256) void sparse_poly_kernel(
    const float4* __restrict__ x, const float* __restrict__ coeffs,
    const float4* __restrict__ mask4, float4* __restrict__ out,
    int n4, int d4mask)
{
    const int idx = blockIdx.x * 256 + (int)threadIdx.x;
    if (idx >= n4) return;

    const float c0 = coeffs[0];
    const float c1 = coeffs[1];
    const float c2 = coeffs[2];

    const float4 m = mask4[idx & d4mask];
    const float4 v = x[idx];

    float4 r;
    r.x = (m.x != 0.0f) ? fmaf(fmaf(c2, v.x, c1), v.x, c0) * v.x : v.x;
    r.y = (m.y != 0.0f) ? fmaf(fmaf(c2, v.y, c1), v.y, c0) * v.y : v.y;
    r.z = (m.z != 0.0f) ? fmaf(fmaf(c2, v.z, c1), v.z, c0) * v.z : v.z;
    r.w = (m.w != 0.0f) ? fmaf(fmaf(c2, v.w, c1), v.w, c0) * v.w : v.w;

    out[idx] = r;
}

extern "C" void kernel_launch(void* const* d_in, const int* in_sizes, int n_in,
                              void* d_out, int out_size, void* d_ws, size_t ws_size,
                              hipStream_t stream) {
    const float* x          = (const float*)d_in[0];   // (B,T,D) fp32
    const float* coeffs     = (const float*)d_in[1];   // (3,) fp32
    const float* importance = (const float*)d_in[2];   // (D,) fp32

    const int D    = in_sizes[2];          // 4096
    const int keep = D / 2;                // keep_ratio = 0.5 -> 2048
    const int n    = in_sizes[0];          // 67108864
    const int n4   = n / 4;

    float* maskf = (float*)d_ws;           // 4096 floats = 16 KB scratch

    // mask: one wave per channel
    topk_mask_kernel<<<D, 64, 0, stream>>>(importance, maskf, D, keep);

    // elementwise: one float4 per thread
    const int blocks = (n4 + 255) / 256;
    sparse_poly_kernel<<<blocks, 256, 0, stream>>>(
        (const float4*)x, coeffs, (const float4*)maskf, (float4*)d_out,
        n4, D / 4 - 1);
}